// Round 14
// baseline (6351.390 us; speedup 1.0000x reference)
//
#include <hip/hip_runtime.h>

#define DI __device__ __forceinline__

constexpr int B_  = 64;
constexpr int T_  = 512;
constexpr int E_  = 256;
constexpr int H_  = 512;
constexpr int G_  = 1536;   // 3*H
constexpr int H2_ = 1024;   // 2*H
constexpr int K_  = 31;
constexpr int BT_ = B_ * T_;
constexpr int TC_ = 64;     // time-chunk length
constexpr int NC_ = T_ / TC_;

typedef float        f32x4  __attribute__((ext_vector_type(4)));
typedef short        bf16x8 __attribute__((ext_vector_type(8)));
typedef unsigned int u32x4  __attribute__((ext_vector_type(4)));
typedef unsigned long long ull;

DI float bf2f(unsigned short u) {
    union { unsigned int i; float f; } v; v.i = ((unsigned int)u) << 16; return v.f;
}
DI unsigned short f2bf(float f) {
    union { float f; unsigned int i; } v; v.f = f;
    unsigned int r = v.i + 0x7fffu + ((v.i >> 16) & 1u);
    return (unsigned short)(r >> 16);
}
DI float sigm(float x) { return 1.f / (1.f + __expf(-x)); }
DI float tanh_(float x) {
    x = fminf(15.f, fmaxf(-15.f, x));
    float e = __expf(-2.f * x);
    return (1.f - e) / (1.f + e);
}

#define MFMA16(a, b, c) __builtin_amdgcn_mfma_f32_16x16x32_bf16(a, b, c, 0, 0, 0)

// ---------------- fp32 -> bf16 convert ----------------
__global__ void cvt_f32_bf16(const float* __restrict__ src, unsigned short* __restrict__ dst, int n) {
    int i = blockIdx.x * blockDim.x + threadIdx.x;
    int stride = gridDim.x * blockDim.x;
    for (; i < n; i += stride) dst[i] = f2bf(src[i]);
}

// classifier weight split halves -> bf16, pad rows 31.. with zeros
__global__ __launch_bounds__(256) void cvt_cls(const float* __restrict__ src,
                                               unsigned short* __restrict__ dstf,
                                               unsigned short* __restrict__ dstb) {
    int i = blockIdx.x * 256 + threadIdx.x;          // [0, 32*512)
    if (i >= 32 * H_) return;
    int n = i >> 9, k = i & 511;
    float vf = (n < K_) ? src[n * H2_ + k] : 0.f;
    float vb = (n < K_) ? src[n * H2_ + H_ + k] : 0.f;
    dstf[i] = f2bf(vf);
    dstb[i] = f2bf(vb);
}

// emissions bias pre-fill (makes later += replay-deterministic)
__global__ __launch_bounds__(256) void emis_bias_init(const float* __restrict__ cls_b,
                                                      float* __restrict__ out1) {
    int i = blockIdx.x * 256 + threadIdx.x;
    int stride = gridDim.x * 256;
    for (; i < BT_ * K_; i += stride) {
        int n = i - (i / K_) * K_;
        out1[i] = cls_b[n];
    }
}

// ---------------- shared GEMM tile body (256 threads, 64x64, bf16 W) ----------------
template <bool OUTF32, bool ACCUM, bool AGATHER>
DI void gemm_tile(unsigned short (*As)[40], unsigned short (*Ws)[40],
                  const unsigned short* A, const float* gsrc, const int* ids, int lda,
                  size_t arow0, const unsigned short* W, int ldw, int nrows, int n0,
                  const float* bias, void* Cout, int ldc, size_t crow0,
                  int nout, int ksz, int tid) {
    const int w = tid >> 6, l = tid & 63;
    const int srow = tid >> 2, sc8 = (tid & 3) * 8;
    const int mw = (w >> 1) * 32, nw = (w & 1) * 32;
    const int fl = l & 15, fk = (l >> 4) * 8;
    f32x4 z4 = { 0.f, 0.f, 0.f, 0.f };
    f32x4 acc[2][2];
    acc[0][0] = z4; acc[0][1] = z4; acc[1][0] = z4; acc[1][1] = z4;
    size_t abase;
    if (AGATHER) abase = (size_t)ids[arow0 + srow] * lda;
    else         abase = (arow0 + srow) * (size_t)lda;

    for (int kc = 0; kc < ksz; kc += 32) {
        u32x4 av, wvv;
        if (AGATHER) {
            const float4* ap = (const float4*)(gsrc + abase + kc + sc8);
            float4 a0 = ap[0], a1 = ap[1];
            union { unsigned short s[8]; u32x4 v; } r;
            r.s[0] = f2bf(a0.x); r.s[1] = f2bf(a0.y); r.s[2] = f2bf(a0.z); r.s[3] = f2bf(a0.w);
            r.s[4] = f2bf(a1.x); r.s[5] = f2bf(a1.y); r.s[6] = f2bf(a1.z); r.s[7] = f2bf(a1.w);
            av = r.v;
        } else {
            av = *(const u32x4*)(A + abase + kc + sc8);
        }
        if (n0 + srow < nrows)
            wvv = *(const u32x4*)(W + (size_t)(n0 + srow) * ldw + kc + sc8);
        else { u32x4 zz = { 0u, 0u, 0u, 0u }; wvv = zz; }
        __syncthreads();
        *(u32x4*)&As[srow][sc8] = av;
        *(u32x4*)&Ws[srow][sc8] = wvv;
        __syncthreads();
        bf16x8 a0 = *(const bf16x8*)&As[mw + fl][fk];
        bf16x8 a1 = *(const bf16x8*)&As[mw + 16 + fl][fk];
        bf16x8 b0 = *(const bf16x8*)&Ws[nw + fl][fk];
        bf16x8 b1 = *(const bf16x8*)&Ws[nw + 16 + fl][fk];
        acc[0][0] = MFMA16(a0, b0, acc[0][0]);
        acc[0][1] = MFMA16(a0, b1, acc[0][1]);
        acc[1][0] = MFMA16(a1, b0, acc[1][0]);
        acc[1][1] = MFMA16(a1, b1, acc[1][1]);
    }

    #pragma unroll
    for (int mf = 0; mf < 2; ++mf)
        #pragma unroll
        for (int nf = 0; nf < 2; ++nf) {
            int col = n0 + nw + nf * 16 + fl;
            if (col >= nout) continue;
            float bv = bias ? bias[col] : 0.f;
            #pragma unroll
            for (int j = 0; j < 4; ++j) {
                int r = mw + mf * 16 + (l >> 4) * 4 + j;
                size_t crow = crow0 + r;
                float v = acc[mf][nf][j] + bv;
                if (OUTF32) {
                    float* C = (float*)Cout;
                    if (ACCUM) C[crow * ldc + col] += v;
                    else       C[crow * ldc + col] = v;
                } else {
                    ((unsigned short*)Cout)[crow * ldc + col] = f2bf(v);
                }
            }
        }
}

template <bool OUTF32, bool ACCUM, bool AGATHER>
__global__ __launch_bounds__(256) void gemm_k(
        const unsigned short* __restrict__ A, const float* __restrict__ gsrc,
        const int* __restrict__ ids, int lda, int m_base, int astride,
        const unsigned short* __restrict__ W, int ldw, int nrows,
        const float* __restrict__ bias,
        void* __restrict__ Cout, int ldc, int c_base, int cstride, int nout, int ksz) {
    __shared__ unsigned short As[64][40];
    __shared__ unsigned short Ws[64][40];
    gemm_tile<OUTF32, ACCUM, AGATHER>(As, Ws, A, gsrc, ids, lda,
        (size_t)m_base + (size_t)blockIdx.x * astride, W, ldw, nrows,
        blockIdx.y * 64, bias, Cout, ldc,
        (size_t)c_base + (size_t)blockIdx.x * cstride, nout, ksz, threadIdx.x);
}

// merged emissions: grid (64,2); y=0 -> gof half, y=1 -> gob half. += into out1.
__global__ __launch_bounds__(256) void emis_k(
        const unsigned short* __restrict__ gof, const unsigned short* __restrict__ gob,
        const unsigned short* __restrict__ clsf, const unsigned short* __restrict__ clsb,
        float* __restrict__ out1, int t0f, int t0b) {
    __shared__ unsigned short As[64][40];
    __shared__ unsigned short Ws[64][40];
    const unsigned short* A = blockIdx.y ? gob : gof;
    const unsigned short* W = blockIdx.y ? clsb : clsf;
    int t0 = blockIdx.y ? t0b : t0f;
    gemm_tile<true, true, false>(As, Ws, A, nullptr, nullptr, H_,
        (size_t)blockIdx.x * TC_, W, H_, 32, 0, nullptr,
        (void*)out1, K_, (size_t)t0 + (size_t)blockIdx.x * T_, K_, H_, threadIdx.x);
}

// ---------------- fused: persistent GRU scan (blocks 0-31, 512 thr) + xp GEMM ----------------
// Scan: 512-thread blocks, 8 waves, 128 units/block -> chain (dir,bg) = 4
// blocks (vs 8): half the exchange traffic (0.5MB/step) and half the straggle
// domain. Per-wave flags (32/chain), 2-parity LDS, one syncthreads/step,
// counted vmcnt drain, busy-then-sleep poll. GEMM blocks: two independent
// 256-thread quarters per block (barrier trip counts align across quarters).
template <bool AGATHER>
__global__ __launch_bounds__(512, 1) void fused_scan_gemm(
        int c, int layer,
        const unsigned short* __restrict__ xpc_f, const unsigned short* __restrict__ xpc_b,
        const unsigned short* __restrict__ whh_f, const unsigned short* __restrict__ whh_b,
        const float* __restrict__ bhh_f, const float* __restrict__ bhh_b,
        unsigned int* __restrict__ hpub,    // [parity][dir][B][256] u32 (2 packed bf16)
        float* __restrict__ hcar,           // [dir][B][H] f32 chunk-carry
        unsigned short* __restrict__ out_f, unsigned short* __restrict__ out_b,
        int ldo, int mode, int* __restrict__ flags,
        const unsigned short* __restrict__ gA, const float* __restrict__ gsrc,
        const int* __restrict__ gids, int glda,
        const unsigned short* __restrict__ gwf, const unsigned short* __restrict__ gwb,
        const float* __restrict__ gbf, const float* __restrict__ gbb,
        unsigned short* __restrict__ xpf_nxt, unsigned short* __restrict__ xpb_nxt,
        int t0f_n, int t0b_n, int do_gemm) {
    __shared__ __align__(16) char smem[40960];
    const int bid = blockIdx.x;
    const int tid = threadIdx.x;

    if (bid >= 32) {                       // ---- GEMM blocks: 2 quarters each ----
        if (!do_gemm) return;
        const int qid = (bid - 32) * 2 + (tid >> 8);      // [0, 384)
        const int ltid = tid & 255;
        char* qb = smem + (size_t)(tid >> 8) * 20480;
        if (AGATHER) {
            // layer-0: 64x64 gather path; 3072 jobs, 384 workers x 8
            unsigned short (*As)[40] = (unsigned short (*)[40])qb;
            unsigned short (*Ws)[40] = (unsigned short (*)[40])(qb + 5120);
            #pragma unroll 1
            for (int job = qid; job < 2 * 64 * 24; job += 384) {
                int dirj = job & 1;
                int rest = job >> 1;
                int mt = rest & 63;
                int nt = rest >> 6;
                const unsigned short* gw = dirj ? gwb : gwf;
                const float* gbias = dirj ? gbb : gbf;
                unsigned short* gout = dirj ? xpb_nxt : xpf_nxt;
                int t0 = dirj ? t0b_n : t0f_n;
                gemm_tile<false, false, true>(As, Ws, gA, gsrc, gids, glda,
                    (size_t)t0 + (size_t)mt * T_, gw, glda, G_, nt * 64, gbias,
                    (void*)gout, G_, (size_t)mt * TC_, G_, glda, ltid);
            }
        } else {
            // layer-1: 128x128 tile; 768 jobs = 384 workers x 2, phase-major
            unsigned short (*A1)[40] = (unsigned short (*)[40])qb;            // [128][40]
            unsigned short (*W1)[40] = (unsigned short (*)[40])(qb + 10240);  // [128][40]
            const int w = ltid >> 6, l = ltid & 63;
            const int fl = l & 15, fk = (l >> 4) * 8;
            const int mw2 = (w >> 1) * 64, nw2 = (w & 1) * 64;
            const int rA = ltid >> 1, ch = (ltid & 1) * 16;
            #pragma unroll 1
            for (int it = 0; it < 2; ++it) {
                int job = it * 384 + qid;      // phase 0 = dir 0, phase 1 = dir 1
                int dirj = (job >= 384) ? 1 : 0;
                int jj = job - dirj * 384;
                int nt = jj >> 5;              // [0,12)
                int mt2 = jj & 31;             // [0,32)
                const unsigned short* gw = dirj ? gwb : gwf;
                const float* gbias = dirj ? gbb : gbf;
                unsigned short* gout = dirj ? xpb_nxt : xpf_nxt;
                int t0 = dirj ? t0b_n : t0f_n;
                int n0j = nt * 128;
                const int mA = mt2 * 2 + (rA >> 6), tlA = rA & 63;
                const unsigned short* aRow = gA + ((size_t)mA * T_ + t0 + tlA) * H2_ + ch;
                const unsigned short* wRow = gw + (size_t)(n0j + rA) * H2_ + ch;
                f32x4 z4 = { 0.f, 0.f, 0.f, 0.f };
                f32x4 acc[4][4];
                #pragma unroll
                for (int a2 = 0; a2 < 4; ++a2)
                    #pragma unroll
                    for (int b2 = 0; b2 < 4; ++b2) acc[a2][b2] = z4;

                for (int kc = 0; kc < H2_; kc += 32) {
                    u32x4 av0 = *(const u32x4*)(aRow + kc);
                    u32x4 av1 = *(const u32x4*)(aRow + kc + 8);
                    u32x4 wv0 = *(const u32x4*)(wRow + kc);
                    u32x4 wv1 = *(const u32x4*)(wRow + kc + 8);
                    __syncthreads();
                    *(u32x4*)&A1[rA][ch] = av0;
                    *(u32x4*)&A1[rA][ch + 8] = av1;
                    *(u32x4*)&W1[rA][ch] = wv0;
                    *(u32x4*)&W1[rA][ch + 8] = wv1;
                    __syncthreads();
                    bf16x8 af[4], bf[4];
                    #pragma unroll
                    for (int a2 = 0; a2 < 4; ++a2) af[a2] = *(const bf16x8*)&A1[mw2 + a2 * 16 + fl][fk];
                    #pragma unroll
                    for (int b2 = 0; b2 < 4; ++b2) bf[b2] = *(const bf16x8*)&W1[nw2 + b2 * 16 + fl][fk];
                    #pragma unroll
                    for (int a2 = 0; a2 < 4; ++a2)
                        #pragma unroll
                        for (int b2 = 0; b2 < 4; ++b2)
                            acc[a2][b2] = MFMA16(af[a2], bf[b2], acc[a2][b2]);
                }

                #pragma unroll
                for (int a2 = 0; a2 < 4; ++a2)
                    #pragma unroll
                    for (int b2 = 0; b2 < 4; ++b2) {
                        int col = n0j + nw2 + b2 * 16 + fl;
                        float bv = gbias[col];
                        #pragma unroll
                        for (int j = 0; j < 4; ++j) {
                            int rloc = mw2 + a2 * 16 + (l >> 4) * 4 + j;
                            int m = mt2 * 2 + (rloc >> 6), tl = rloc & 63;
                            gout[((size_t)m * TC_ + tl) * G_ + col] = f2bf(acc[a2][b2][j] + bv);
                        }
                    }
            }
        }
        return;
    }

    // ---- scan blocks: bid = dir*16 + ug*4 + bg ----
    const int dir = bid >> 4;
    const int rest = bid & 15;
    const int ug  = rest >> 2;             // unit-group [0,4), 128 units each
    const int bg  = rest & 3;              // batch-group [0,4)
    const int w = tid >> 6, l = tid & 63;  // 8 waves
    const int fl = l & 15, q = l >> 4, fko = q * 8;
    const unsigned short* xp = dir ? xpc_b : xpc_f;
    const unsigned short* whh = dir ? whh_b : whh_f;   // bf16
    const float* bhh = dir ? bhh_b : bhh_f;
    unsigned short* outp = dir ? out_b : out_f;
    int* pollb  = flags + (dir * 4 + bg) * 32 * 32;  // 32 wave-flags (4 blk x 8 w)
    int* myflag = pollb + (ug * 8 + w) * 32;

    // W_hh (bf16) -> VGPR fragments, once per chunk
    const int u0w = ug * 128 + w * 16;
    bf16x8 wv[3][16];
    #pragma unroll
    for (int g = 0; g < 3; ++g)
        #pragma unroll
        for (int ks = 0; ks < 16; ++ks)
            wv[g][ks] = *(const bf16x8*)(whh + (size_t)(g * H_ + u0w + fl) * H_ + ks * 32 + fko);

    const int u = u0w + fl;
    const float br_ = bhh[u], bz_ = bhh[H_ + u], bn_ = bhh[2 * H_ + u];
    const int mb = bg * 16 + q * 4;        // epilogue batch base (4 rows)
    const int srowl = tid >> 5;            // stage: local row [0,16)
    const int sseg  = tid & 31;            // stage: 32B segment

    float hp[4];
    if (c > 0) {
        #pragma unroll
        for (int j = 0; j < 4; ++j) hp[j] = hcar[dir * (B_ * H_) + (mb + j) * H_ + u];
    } else {
        #pragma unroll
        for (int j = 0; j < 4; ++j) hp[j] = 0.f;
    }

    unsigned short xg[3][4];
    auto ldxp = [&](int tl) {
        #pragma unroll
        for (int j = 0; j < 4; ++j) {
            const unsigned short* xb = xp + ((size_t)((mb + j) * TC_ + tl) * G_) + u;
            xg[0][j] = xb[0]; xg[1][j] = xb[H_]; xg[2][j] = xb[2 * H_];
        }
    };
    ldxp(dir ? (TC_ - 1) : 0);

    for (int sl = 0; sl < TC_; ++sl) {
        const int s  = c * TC_ + sl;
        const int gs = layer * T_ + s;
        const int t = dir ? (T_ - 1 - s) : s;
        const int tloc = dir ? (TC_ - 1 - sl) : sl;

        f32x4 z4 = { 0.f, 0.f, 0.f, 0.f };
        f32x4 acc[3];
        acc[0] = z4; acc[1] = z4; acc[2] = z4;

        if (s > 0) {
            const unsigned int rpar = (unsigned int)(((s - 1) & 1) * 16384);
            if (sl > 0) {                  // chunk start: prev launch done via stream order
                int v = gs;
                int tries = 0;
                if (l < 32) v = __hip_atomic_load(pollb + l * 32, __ATOMIC_RELAXED, __HIP_MEMORY_SCOPE_AGENT);
                while (!__all(v >= gs)) {
                    if (++tries > 3) __builtin_amdgcn_s_sleep(1);
                    if (l < 32) v = __hip_atomic_load(pollb + l * 32, __ATOMIC_RELAXED, __HIP_MEMORY_SCOPE_AGENT);
                }
                asm volatile("" ::: "memory");   // no hoist of h loads above poll
            }
            // cooperative stage: h(s-1)[bg*16 .. +15][all 512] -> parity LDS (swizzled)
            {
                const ull* src = (const ull*)(hpub
                    + ((size_t)((((s - 1) & 1) * 2 + dir) * B_ + bg * 16 + srowl)) * 256)
                    + sseg * 4;
                ull qv[4];
                #pragma unroll
                for (int i = 0; i < 4; ++i)
                    qv[i] = __hip_atomic_load(src + i, __ATOMIC_RELAXED, __HIP_MEMORY_SCOPE_AGENT);
                char* dst = smem + rpar + srowl * 1024;
                #pragma unroll
                for (int i = 0; i < 2; ++i) {
                    unsigned int byt = (unsigned int)(sseg * 32 + i * 16);
                    byt ^= ((unsigned int)(srowl & 7)) << 4;
                    union { ull qq[2]; u32x4 v4; } pk;
                    pk.qq[0] = qv[2 * i]; pk.qq[1] = qv[2 * i + 1];
                    *(u32x4*)(dst + byt) = pk.v4;
                }
            }
            __syncthreads();               // the single per-step barrier (stage -> read)
            #pragma unroll
            for (int ks = 0; ks < 16; ++ks) {
                unsigned int byt = (unsigned int)(ks * 64 + q * 16);
                byt ^= ((unsigned int)(fl & 7)) << 4;
                bf16x8 afr = *(const bf16x8*)(smem + rpar + fl * 1024 + byt);
                acc[0] = MFMA16(afr, wv[0][ks], acc[0]);
                acc[1] = MFMA16(afr, wv[1][ks], acc[1]);
                acc[2] = MFMA16(afr, wv[2][ks], acc[2]);
            }
        }

        unsigned short hb16s[4];
        #pragma unroll
        for (int j = 0; j < 4; ++j) {
            float xr = bf2f(xg[0][j]);
            float xz = bf2f(xg[1][j]);
            float xn = bf2f(xg[2][j]);
            float r = sigm(xr + acc[0][j] + br_);
            float z = sigm(xz + acc[1][j] + bz_);
            float nn = tanh_(xn + r * (acc[2][j] + bn_));
            float hv = (1.f - z) * nn + z * hp[j];
            hp[j] = hv;
            hb16s[j] = f2bf(hv);
        }

        // packed h stores (even-fl lanes) FIRST ...
        unsigned int* hw = hpub + (size_t)((s & 1) * 2 + dir) * (B_ * 256);
        #pragma unroll
        for (int j = 0; j < 4; ++j) {
            unsigned int pv = (unsigned int)(unsigned short)__shfl_xor((int)hb16s[j], 1);
            if ((fl & 1) == 0) {
                unsigned int pk32 = (unsigned int)hb16s[j] | (pv << 16);
                __hip_atomic_store(hw + (size_t)(mb + j) * 256 + (u >> 1), pk32,
                                   __ATOMIC_RELAXED, __HIP_MEMORY_SCOPE_AGENT);
            }
        }
        asm volatile("" ::: "memory");     // pin issue order: h stores before the below
        // ... then outp stores + next-xp prefetch issue UNDER the h-store ack RT
        #pragma unroll
        for (int j = 0; j < 4; ++j) {
            size_t row = mode ? (size_t)((mb + j) * TC_ + tloc) : ((size_t)(mb + j) * T_ + t);
            outp[row * ldo + u] = hb16s[j];
        }
        if (sl < TC_ - 1) ldxp(dir ? (TC_ - 2 - sl) : (sl + 1));
        // counted wait: <=16 outstanding => the 4 older h stores are acked
        asm volatile("s_waitcnt vmcnt(16)" ::: "memory");
        if (l == 0)                        // per-WAVE flag: own 16-unit slice done
            __hip_atomic_store(myflag, gs + 1, __ATOMIC_RELAXED, __HIP_MEMORY_SCOPE_AGENT);
    }

    #pragma unroll
    for (int j = 0; j < 4; ++j) hcar[dir * (B_ * H_) + (mb + j) * H_ + u] = hp[j];
}

// ---------------- CRF: one block (one wave) per batch element ----------------
__global__ __launch_bounds__(64) void crf_kernel(const float* __restrict__ em,     // [BT][K]
                                                 const int* __restrict__ labels,
                                                 const float* __restrict__ start,
                                                 const float* __restrict__ endv,
                                                 const float* __restrict__ trans,
                                                 float* __restrict__ partials) {
    __shared__ float tr[32 * 32];
    const int b = blockIdx.x, l = threadIdx.x;
    for (int e2 = l; e2 < 961; e2 += 64) {
        int r = e2 / 31, cc = e2 - r * 31;
        tr[r * 32 + cc] = trans[e2];
    }
    if (l < 32) tr[31 * 32 + l] = 0.f;
    __syncthreads();
    const int* lab = labels + b * T_;
    const float* eb = em + (size_t)b * T_ * K_;

    float part = 0.f, cnt = 0.f;
    for (int t = l; t < T_; t += 64) {
        int lt = lab[t];
        if (lt > -1) {
            cnt += 1.f;
            if (t > 0) part += tr[lab[t - 1] * 32 + lt] + eb[t * K_ + lt];
        }
    }
    #pragma unroll
    for (int o = 32; o; o >>= 1) { part += __shfl_xor(part, o); cnt += __shfl_xor(cnt, o); }
    int lastidx = (int)cnt - 1;
    float num = part + start[lab[0]] + eb[lab[0]] + endv[lab[lastidx]];

    const int jj = l & 31, half = l >> 5;
    const int i0 = half * 16;
    const int ecol = (jj < K_) ? jj : (K_ - 1);
    float a = (jj < K_) ? (start[jj] + eb[jj]) : -3.0e38f;
    for (int t = 1; t < T_; ++t) {
        float tv[16];
        float m = -3.0e38f;
        #pragma unroll
        for (int k = 0; k < 16; ++k) {
            float av = __shfl(a, i0 + k);
            float x = av + tr[(i0 + k) * 32 + jj];
            tv[k] = x;
            m = fmaxf(m, x);
        }
        float ss = 0.f;
        #pragma unroll
        for (int k = 0; k < 16; ++k) ss += __expf(tv[k] - m);
        float m2 = __shfl_xor(m, 32), s2 = __shfl_xor(ss, 32);
        float M = fmaxf(m, m2);
        float S = ss * __expf(m - M) + s2 * __expf(m2 - M);
        float anew = eb[t * K_ + ecol] + M + __logf(S);
        a = ((lab[t] > -1) && (jj < K_)) ? anew : a;
    }
    float v = (jj < K_) ? (a + endv[jj]) : -3.0e38f;
    float m = v;
    #pragma unroll
    for (int o = 32; o; o >>= 1) m = fmaxf(m, __shfl_xor(m, o));
    float ss = (half == 0 && jj < K_) ? __expf(v - m) : 0.f;
    #pragma unroll
    for (int o = 32; o; o >>= 1) ss += __shfl_xor(ss, o);
    if (l == 0) partials[b] = num - (m + __logf(ss));
}

__global__ __launch_bounds__(64) void loss_reduce(const float* __restrict__ partials,
                                                  float* __restrict__ out) {
    float v = partials[threadIdx.x];
    #pragma unroll
    for (int o = 32; o; o >>= 1) v += __shfl_xor(v, o);
    if (threadIdx.x == 0) out[0] = -v;
}

__global__ void sentinel(float* __restrict__ out, float v) { out[0] = -v; }

// ---------------- host ----------------
extern "C" void kernel_launch(void* const* d_in, const int* in_sizes, int n_in,
                              void* d_out, int out_size, void* d_ws, size_t ws_size,
                              hipStream_t stream) {
    const int*   ids      = (const int*)d_in[0];
    const int*   labels   = (const int*)d_in[1];
    const float* emb      = (const float*)d_in[2];
    const float* wih[4]   = { (const float*)d_in[3], (const float*)d_in[7], (const float*)d_in[11], (const float*)d_in[15] };
    const float* whh[4]   = { (const float*)d_in[4], (const float*)d_in[8], (const float*)d_in[12], (const float*)d_in[16] };
    const float* bih[4]   = { (const float*)d_in[5], (const float*)d_in[9], (const float*)d_in[13], (const float*)d_in[17] };
    const float* bhh[4]   = { (const float*)d_in[6], (const float*)d_in[10], (const float*)d_in[14], (const float*)d_in[18] };
    const float* cls_w    = (const float*)d_in[19];
    const float* cls_b    = (const float*)d_in[20];
    const float* c_start  = (const float*)d_in[21];
    const float* c_end    = (const float*)d_in[22];
    const float* c_trans  = (const float*)d_in[23];
    float* out = (float*)d_out;
    float* out1 = out + 1;

    char* p = (char*)d_ws;
    size_t used = 0;
    auto alloc = [&](size_t bytes) -> char* {
        char* r = p;
        size_t a = (bytes + 255) & ~(size_t)255;
        p += a; used += a;
        return r;
    };
    unsigned short* xpF[2]; unsigned short* xpB[2];
    for (int i = 0; i < 2; ++i) {
        xpF[i] = (unsigned short*)alloc((size_t)B_ * TC_ * G_ * 2);   // 12.6MB each
        xpB[i] = (unsigned short*)alloc((size_t)B_ * TC_ * G_ * 2);
    }
    unsigned short* h1   = (unsigned short*)alloc((size_t)BT_ * H2_ * 2);       // 67MB
    unsigned short* gof  = (unsigned short*)alloc((size_t)B_ * TC_ * H_ * 2);   // 4.2MB
    unsigned short* gob  = (unsigned short*)alloc((size_t)B_ * TC_ * H_ * 2);
    unsigned short* clsf  = (unsigned short*)alloc((size_t)32 * H_ * 2);
    unsigned short* clshb = (unsigned short*)alloc((size_t)32 * H_ * 2);
    unsigned short* whhbf = (unsigned short*)alloc((size_t)G_ * H_ * 2);        // per-layer, re-cvt
    unsigned short* whhbb = (unsigned short*)alloc((size_t)G_ * H_ * 2);
    unsigned short* wihbf = (unsigned short*)alloc((size_t)G_ * H2_ * 2);       // 3.1MB, per-layer
    unsigned short* wihbb = (unsigned short*)alloc((size_t)G_ * H2_ * 2);
    unsigned int*   hpub  = (unsigned int*)alloc((size_t)2 * 2 * B_ * 256 * 4); // 512KB
    float*          hcar  = (float*)alloc((size_t)2 * B_ * H_ * 4);             // 256KB
    float*          partials = (float*)alloc((size_t)B_ * 4);
    int*            flags = (int*)alloc((size_t)2 * 4 * 32 * 32 * 4);           // 32KB

    if (used > ws_size) {
        sentinel<<<dim3(1), dim3(1), 0, stream>>>(out, (float)(ws_size >> 20));
        return;
    }

    hipMemsetAsync(flags, 0, (size_t)2 * 4 * 32 * 32 * 4, stream);
    cvt_cls<<<dim3((32 * H_ + 255) / 256), dim3(256), 0, stream>>>(cls_w, clsf, clshb);
    emis_bias_init<<<dim3(1024), dim3(256), 0, stream>>>(cls_b, out1);

    for (int layer = 0; layer < 2; ++layer) {
        const float* bf_ = bih[layer * 2 + 0];
        const float* bb_ = bih[layer * 2 + 1];
        const float* bhf = bhh[layer * 2 + 0];
        const float* bhb = bhh[layer * 2 + 1];
        const int lda = layer ? H2_ : E_;

        // convert this layer's weights -> bf16 (stream-ordered, deterministic)
        cvt_f32_bf16<<<dim3(2048), dim3(256), 0, stream>>>(whh[layer * 2 + 0], whhbf, G_ * H_);
        cvt_f32_bf16<<<dim3(2048), dim3(256), 0, stream>>>(whh[layer * 2 + 1], whhbb, G_ * H_);
        cvt_f32_bf16<<<dim3(2048), dim3(256), 0, stream>>>(wih[layer * 2 + 0], wihbf, G_ * lda);
        cvt_f32_bf16<<<dim3(2048), dim3(256), 0, stream>>>(wih[layer * 2 + 1], wihbb, G_ * lda);

        // chunk-0 xp GEMMs (standalone, full grid, bf16 W)
        if (layer == 0) {
            gemm_k<false, false, true><<<dim3(64, 24), dim3(256), 0, stream>>>(
                nullptr, emb, ids, E_, 0, T_, wihbf, E_, G_, bf_, (void*)xpF[0], G_, 0, TC_, G_, E_);
            gemm_k<false, false, true><<<dim3(64, 24), dim3(256), 0, stream>>>(
                nullptr, emb, ids, E_, T_ - TC_, T_, wihbb, E_, G_, bb_, (void*)xpB[0], G_, 0, TC_, G_, E_);
        } else {
            gemm_k<false, false, false><<<dim3(64, 24), dim3(256), 0, stream>>>(
                h1, nullptr, nullptr, H2_, 0, T_, wihbf, H2_, G_, bf_, (void*)xpF[0], G_, 0, TC_, G_, H2_);
            gemm_k<false, false, false><<<dim3(64, 24), dim3(256), 0, stream>>>(
                h1, nullptr, nullptr, H2_, T_ - TC_, T_, wihbb, H2_, G_, bb_, (void*)xpB[0], G_, 0, TC_, G_, H2_);
        }

        for (int c = 0; c < NC_; ++c) {
            int dg = (c + 1 < NC_) ? 1 : 0;
            int t0f_n = (c + 1) * TC_;
            int t0b_n = T_ - (c + 2) * TC_;
            if (layer == 0) {
                fused_scan_gemm<true><<<dim3(224), dim3(512), 0, stream>>>(
                    c, 0, xpF[c & 1], xpB[c & 1], whhbf, whhbb, bhf, bhb, hpub, hcar,
                    h1, h1 + H_, H2_, 0, flags,
                    nullptr, emb, ids, E_, wihbf, wihbb, bf_, bb_,
                    xpF[(c + 1) & 1], xpB[(c + 1) & 1], t0f_n, t0b_n, dg);
            } else {
                fused_scan_gemm<false><<<dim3(224), dim3(512), 0, stream>>>(
                    c, 1, xpF[c & 1], xpB[c & 1], whhbf, whhbb, bhf, bhb, hpub, hcar,
                    gof, gob, H_, 1, flags,
                    h1, nullptr, nullptr, H2_, wihbf, wihbb, bf_, bb_,
                    xpF[(c + 1) & 1], xpB[(c + 1) & 1], t0f_n, t0b_n, dg);
                // emissions for this chunk (merged pair, += into out1)
                int t0f = c * TC_;
                int t0b = T_ - (c + 1) * TC_;
                emis_k<<<dim3(64, 2), dim3(256), 0, stream>>>(gof, gob, clsf, clshb, out1, t0f, t0b);
            }
        }
    }

    crf_kernel<<<dim3(B_), dim3(64), 0, stream>>>(out1, labels, c_start, c_end, c_trans, partials);
    loss_reduce<<<dim3(1), dim3(64), 0, stream>>>(partials, out);
}

// Round 15
// 4148.956 us; speedup vs baseline: 1.5308x; 1.5308x over previous
//
#include <hip/hip_runtime.h>

#define DI __device__ __forceinline__

constexpr int B_  = 64;
constexpr int T_  = 512;
constexpr int E_  = 256;
constexpr int H_  = 512;
constexpr int G_  = 1536;   // 3*H
constexpr int H2_ = 1024;   // 2*H
constexpr int K_  = 31;
constexpr int BT_ = B_ * T_;
constexpr int TC_ = 64;     // time-chunk length
constexpr int NC_ = T_ / TC_;

typedef float        f32x4  __attribute__((ext_vector_type(4)));
typedef short        bf16x8 __attribute__((ext_vector_type(8)));
typedef unsigned int u32x4  __attribute__((ext_vector_type(4)));
typedef unsigned long long ull;

DI float bf2f(unsigned short u) {
    union { unsigned int i; float f; } v; v.i = ((unsigned int)u) << 16; return v.f;
}
DI unsigned short f2bf(float f) {
    union { float f; unsigned int i; } v; v.f = f;
    unsigned int r = v.i + 0x7fffu + ((v.i >> 16) & 1u);
    return (unsigned short)(r >> 16);
}
DI float sigm(float x) { return 1.f / (1.f + __expf(-x)); }
DI float tanh_(float x) {
    x = fminf(15.f, fmaxf(-15.f, x));
    float e = __expf(-2.f * x);
    return (1.f - e) / (1.f + e);
}

#define MFMA16(a, b, c) __builtin_amdgcn_mfma_f32_16x16x32_bf16(a, b, c, 0, 0, 0)

// ---------------- fp32 -> bf16 convert ----------------
__global__ void cvt_f32_bf16(const float* __restrict__ src, unsigned short* __restrict__ dst, int n) {
    int i = blockIdx.x * blockDim.x + threadIdx.x;
    int stride = gridDim.x * blockDim.x;
    for (; i < n; i += stride) dst[i] = f2bf(src[i]);
}

// classifier weight split halves -> bf16, pad rows 31.. with zeros
__global__ __launch_bounds__(256) void cvt_cls(const float* __restrict__ src,
                                               unsigned short* __restrict__ dstf,
                                               unsigned short* __restrict__ dstb) {
    int i = blockIdx.x * 256 + threadIdx.x;          // [0, 32*512)
    if (i >= 32 * H_) return;
    int n = i >> 9, k = i & 511;
    float vf = (n < K_) ? src[n * H2_ + k] : 0.f;
    float vb = (n < K_) ? src[n * H2_ + H_ + k] : 0.f;
    dstf[i] = f2bf(vf);
    dstb[i] = f2bf(vb);
}

// emissions bias pre-fill (makes later += replay-deterministic)
__global__ __launch_bounds__(256) void emis_bias_init(const float* __restrict__ cls_b,
                                                      float* __restrict__ out1) {
    int i = blockIdx.x * 256 + threadIdx.x;
    int stride = gridDim.x * 256;
    for (; i < BT_ * K_; i += stride) {
        int n = i - (i / K_) * K_;
        out1[i] = cls_b[n];
    }
}

// ---------------- shared GEMM tile body (256 threads, 64x64, bf16 W) ----------------
template <bool OUTF32, bool ACCUM, bool AGATHER>
DI void gemm_tile(unsigned short (*As)[40], unsigned short (*Ws)[40],
                  const unsigned short* A, const float* gsrc, const int* ids, int lda,
                  size_t arow0, const unsigned short* W, int ldw, int nrows, int n0,
                  const float* bias, void* Cout, int ldc, size_t crow0,
                  int nout, int ksz, int tid) {
    const int w = tid >> 6, l = tid & 63;
    const int srow = tid >> 2, sc8 = (tid & 3) * 8;
    const int mw = (w >> 1) * 32, nw = (w & 1) * 32;
    const int fl = l & 15, fk = (l >> 4) * 8;
    f32x4 z4 = { 0.f, 0.f, 0.f, 0.f };
    f32x4 acc[2][2];
    acc[0][0] = z4; acc[0][1] = z4; acc[1][0] = z4; acc[1][1] = z4;
    size_t abase;
    if (AGATHER) abase = (size_t)ids[arow0 + srow] * lda;
    else         abase = (arow0 + srow) * (size_t)lda;

    for (int kc = 0; kc < ksz; kc += 32) {
        u32x4 av, wvv;
        if (AGATHER) {
            const float4* ap = (const float4*)(gsrc + abase + kc + sc8);
            float4 a0 = ap[0], a1 = ap[1];
            union { unsigned short s[8]; u32x4 v; } r;
            r.s[0] = f2bf(a0.x); r.s[1] = f2bf(a0.y); r.s[2] = f2bf(a0.z); r.s[3] = f2bf(a0.w);
            r.s[4] = f2bf(a1.x); r.s[5] = f2bf(a1.y); r.s[6] = f2bf(a1.z); r.s[7] = f2bf(a1.w);
            av = r.v;
        } else {
            av = *(const u32x4*)(A + abase + kc + sc8);
        }
        if (n0 + srow < nrows)
            wvv = *(const u32x4*)(W + (size_t)(n0 + srow) * ldw + kc + sc8);
        else { u32x4 zz = { 0u, 0u, 0u, 0u }; wvv = zz; }
        __syncthreads();
        *(u32x4*)&As[srow][sc8] = av;
        *(u32x4*)&Ws[srow][sc8] = wvv;
        __syncthreads();
        bf16x8 a0 = *(const bf16x8*)&As[mw + fl][fk];
        bf16x8 a1 = *(const bf16x8*)&As[mw + 16 + fl][fk];
        bf16x8 b0 = *(const bf16x8*)&Ws[nw + fl][fk];
        bf16x8 b1 = *(const bf16x8*)&Ws[nw + 16 + fl][fk];
        acc[0][0] = MFMA16(a0, b0, acc[0][0]);
        acc[0][1] = MFMA16(a0, b1, acc[0][1]);
        acc[1][0] = MFMA16(a1, b0, acc[1][0]);
        acc[1][1] = MFMA16(a1, b1, acc[1][1]);
    }

    #pragma unroll
    for (int mf = 0; mf < 2; ++mf)
        #pragma unroll
        for (int nf = 0; nf < 2; ++nf) {
            int col = n0 + nw + nf * 16 + fl;
            if (col >= nout) continue;
            float bv = bias ? bias[col] : 0.f;
            #pragma unroll
            for (int j = 0; j < 4; ++j) {
                int r = mw + mf * 16 + (l >> 4) * 4 + j;
                size_t crow = crow0 + r;
                float v = acc[mf][nf][j] + bv;
                if (OUTF32) {
                    float* C = (float*)Cout;
                    if (ACCUM) C[crow * ldc + col] += v;
                    else       C[crow * ldc + col] = v;
                } else {
                    ((unsigned short*)Cout)[crow * ldc + col] = f2bf(v);
                }
            }
        }
}

template <bool OUTF32, bool ACCUM, bool AGATHER>
__global__ __launch_bounds__(256) void gemm_k(
        const unsigned short* __restrict__ A, const float* __restrict__ gsrc,
        const int* __restrict__ ids, int lda, int m_base, int astride,
        const unsigned short* __restrict__ W, int ldw, int nrows,
        const float* __restrict__ bias,
        void* __restrict__ Cout, int ldc, int c_base, int cstride, int nout, int ksz) {
    __shared__ unsigned short As[64][40];
    __shared__ unsigned short Ws[64][40];
    gemm_tile<OUTF32, ACCUM, AGATHER>(As, Ws, A, gsrc, ids, lda,
        (size_t)m_base + (size_t)blockIdx.x * astride, W, ldw, nrows,
        blockIdx.y * 64, bias, Cout, ldc,
        (size_t)c_base + (size_t)blockIdx.x * cstride, nout, ksz, threadIdx.x);
}

// merged emissions: grid (64,2); y=0 -> gof half, y=1 -> gob half. += into out1.
__global__ __launch_bounds__(256) void emis_k(
        const unsigned short* __restrict__ gof, const unsigned short* __restrict__ gob,
        const unsigned short* __restrict__ clsf, const unsigned short* __restrict__ clsb,
        float* __restrict__ out1, int t0f, int t0b) {
    __shared__ unsigned short As[64][40];
    __shared__ unsigned short Ws[64][40];
    const unsigned short* A = blockIdx.y ? gob : gof;
    const unsigned short* W = blockIdx.y ? clsb : clsf;
    int t0 = blockIdx.y ? t0b : t0f;
    gemm_tile<true, true, false>(As, Ws, A, nullptr, nullptr, H_,
        (size_t)blockIdx.x * TC_, W, H_, 32, 0, nullptr,
        (void*)out1, K_, (size_t)t0 + (size_t)blockIdx.x * T_, K_, H_, threadIdx.x);
}

// ---------------- fused: persistent GRU scan (blocks 0-63) + next-chunk xp GEMM ----------------
// r13 structure exactly (proven 252us/dispatch): 256-thread blocks; per dir
// 32 blocks = 8 unit-groups x 4 batch-groups; per-wave flags, 2-parity LDS,
// one syncthreads/step, counted vmcnt drain. Deltas: busy-then-sleep poll;
// layer-1 GEMM blocks additionally apply the PREVIOUS chunk's emissions
// (go buffers double-buffered; stream order makes reads safe).
template <bool AGATHER>
__global__ __launch_bounds__(256, 1) void fused_scan_gemm(
        int c, int layer,
        const unsigned short* __restrict__ xpc_f, const unsigned short* __restrict__ xpc_b,
        const unsigned short* __restrict__ whh_f, const unsigned short* __restrict__ whh_b,
        const float* __restrict__ bhh_f, const float* __restrict__ bhh_b,
        unsigned int* __restrict__ hpub,    // [parity][dir][B][256] u32 (2 packed bf16)
        float* __restrict__ hcar,           // [dir][B][H] f32 chunk-carry
        unsigned short* __restrict__ out_f, unsigned short* __restrict__ out_b,
        int ldo, int mode, int* __restrict__ flags,
        const unsigned short* __restrict__ gA, const float* __restrict__ gsrc,
        const int* __restrict__ gids, int glda,
        const unsigned short* __restrict__ gwf, const unsigned short* __restrict__ gwb,
        const float* __restrict__ gbf, const float* __restrict__ gbb,
        unsigned short* __restrict__ xpf_nxt, unsigned short* __restrict__ xpb_nxt,
        int t0f_n, int t0b_n, int do_gemm,
        const unsigned short* __restrict__ egof, const unsigned short* __restrict__ egob,
        const unsigned short* __restrict__ clsf, const unsigned short* __restrict__ clsb,
        float* __restrict__ out1, int t0f_e, int t0b_e, int do_emis) {
    __shared__ __align__(16) char smem[32768];
    const int bid = blockIdx.x;
    const int tid = threadIdx.x;

    if (bid >= 64) {                       // ---- GEMM blocks ----
        const int gb = bid - 64;
        if (AGATHER) {
            if (!do_gemm) return;
            // layer-0: 64x64 gather path, bf16 W
            unsigned short (*As)[40] = (unsigned short (*)[40])smem;
            unsigned short (*Ws)[40] = (unsigned short (*)[40])(smem + 5120);
            for (int job = gb; job < 2 * 64 * 24; job += 192) {
                int dirj = job & 1;
                int rest = job >> 1;
                int mt = rest & 63;
                int nt = rest >> 6;
                const unsigned short* gw = dirj ? gwb : gwf;
                const float* gbias = dirj ? gbb : gbf;
                unsigned short* gout = dirj ? xpb_nxt : xpf_nxt;
                int t0 = dirj ? t0b_n : t0f_n;
                gemm_tile<false, false, true>(As, Ws, gA, gsrc, gids, glda,
                    (size_t)t0 + (size_t)mt * T_, gw, glda, G_, nt * 64, gbias,
                    (void*)gout, G_, (size_t)mt * TC_, G_, glda, tid);
            }
        } else {
            // layer-1: 128x128 tile, bf16 W, phase order it*192+gb (L2-friendly)
            if (do_gemm) {
                unsigned short (*A1)[40] = (unsigned short (*)[40])smem;            // [128][40]
                unsigned short (*W1)[40] = (unsigned short (*)[40])(smem + 10240);  // [128][40]
                const int w = tid >> 6, l = tid & 63;
                const int fl = l & 15, fk = (l >> 4) * 8;
                const int mw2 = (w >> 1) * 64, nw2 = (w & 1) * 64;
                const int rA = tid >> 1, ch = (tid & 1) * 16;   // stage row, col-half
                #pragma unroll 1
                for (int it = 0; it < 4; ++it) {
                    int job = it * 192 + gb;       // phase-major: share 6 W tiles/phase
                    int dirj = (job >= 384) ? 1 : 0;
                    int jj = job - dirj * 384;
                    int nt = jj >> 5;              // [0,12)
                    int mt2 = jj & 31;             // [0,32)
                    const unsigned short* gw = dirj ? gwb : gwf;
                    const float* gbias = dirj ? gbb : gbf;
                    unsigned short* gout = dirj ? xpb_nxt : xpf_nxt;
                    int t0 = dirj ? t0b_n : t0f_n;
                    int n0j = nt * 128;
                    const int mA = mt2 * 2 + (rA >> 6), tlA = rA & 63;
                    const unsigned short* aRow = gA + ((size_t)mA * T_ + t0 + tlA) * H2_ + ch;
                    const unsigned short* wRow = gw + (size_t)(n0j + rA) * H2_ + ch;
                    f32x4 z4 = { 0.f, 0.f, 0.f, 0.f };
                    f32x4 acc[4][4];
                    #pragma unroll
                    for (int a2 = 0; a2 < 4; ++a2)
                        #pragma unroll
                        for (int b2 = 0; b2 < 4; ++b2) acc[a2][b2] = z4;

                    for (int kc = 0; kc < H2_; kc += 32) {
                        u32x4 av0 = *(const u32x4*)(aRow + kc);
                        u32x4 av1 = *(const u32x4*)(aRow + kc + 8);
                        u32x4 wv0 = *(const u32x4*)(wRow + kc);
                        u32x4 wv1 = *(const u32x4*)(wRow + kc + 8);
                        __syncthreads();
                        *(u32x4*)&A1[rA][ch] = av0;
                        *(u32x4*)&A1[rA][ch + 8] = av1;
                        *(u32x4*)&W1[rA][ch] = wv0;
                        *(u32x4*)&W1[rA][ch + 8] = wv1;
                        __syncthreads();
                        bf16x8 af[4], bf[4];
                        #pragma unroll
                        for (int a2 = 0; a2 < 4; ++a2) af[a2] = *(const bf16x8*)&A1[mw2 + a2 * 16 + fl][fk];
                        #pragma unroll
                        for (int b2 = 0; b2 < 4; ++b2) bf[b2] = *(const bf16x8*)&W1[nw2 + b2 * 16 + fl][fk];
                        #pragma unroll
                        for (int a2 = 0; a2 < 4; ++a2)
                            #pragma unroll
                            for (int b2 = 0; b2 < 4; ++b2)
                                acc[a2][b2] = MFMA16(af[a2], bf[b2], acc[a2][b2]);
                    }

                    #pragma unroll
                    for (int a2 = 0; a2 < 4; ++a2)
                        #pragma unroll
                        for (int b2 = 0; b2 < 4; ++b2) {
                            int col = n0j + nw2 + b2 * 16 + fl;
                            float bv = gbias[col];
                            #pragma unroll
                            for (int j = 0; j < 4; ++j) {
                                int rloc = mw2 + a2 * 16 + (l >> 4) * 4 + j;
                                int m = mt2 * 2 + (rloc >> 6), tl = rloc & 63;
                                gout[((size_t)m * TC_ + tl) * G_ + col] = f2bf(acc[a2][b2][j] + bv);
                            }
                        }
                }
            }
            // folded emissions for the previous chunk (128 jobs on gb<128)
            if (do_emis && gb < 128) {
                int dirj = gb >> 6, mt = gb & 63;
                const unsigned short* A = dirj ? egob : egof;
                const unsigned short* W = dirj ? clsb : clsf;
                int t0 = dirj ? t0b_e : t0f_e;
                gemm_tile<true, true, false>((unsigned short (*)[40])smem,
                    (unsigned short (*)[40])(smem + 5120),
                    A, nullptr, nullptr, H_, (size_t)mt * TC_, W, H_, 32, 0, nullptr,
                    (void*)out1, K_, (size_t)t0 + (size_t)mt * T_, K_, H_, tid);
            }
        }
        return;
    }

    // ---- scan blocks ----
    const int dir = bid >> 5;
    const int rb  = bid & 31;
    const int ug  = rb >> 2;               // unit-group [0,8)
    const int bg  = rb & 3;                // batch-group [0,4)
    const int w = tid >> 6, l = tid & 63;
    const int fl = l & 15, q = l >> 4, fko = q * 8;
    const unsigned short* xp = dir ? xpc_b : xpc_f;
    const unsigned short* whh = dir ? whh_b : whh_f;   // bf16
    const float* bhh = dir ? bhh_b : bhh_f;
    unsigned short* outp = dir ? out_b : out_f;
    int* pollb  = flags + (dir * 4 + bg) * 32 * 32;  // 32 wave-flags, 128B apart
    int* myflag = pollb + (ug * 4 + w) * 32;

    // W_hh (bf16) -> VGPR fragments, once per chunk
    const int u0w = ug * 64 + w * 16;
    bf16x8 wv[3][16];
    #pragma unroll
    for (int g = 0; g < 3; ++g)
        #pragma unroll
        for (int ks = 0; ks < 16; ++ks)
            wv[g][ks] = *(const bf16x8*)(whh + (size_t)(g * H_ + u0w + fl) * H_ + ks * 32 + fko);

    const int u = u0w + fl;
    const float br_ = bhh[u], bz_ = bhh[H_ + u], bn_ = bhh[2 * H_ + u];
    const int mb = bg * 16 + q * 4;        // epilogue batch base (4 rows)
    const int srowl = tid >> 4;            // stage: local row [0,16)
    const int sseg  = tid & 15;            // stage: 64B segment

    float hp[4];
    if (c > 0) {
        #pragma unroll
        for (int j = 0; j < 4; ++j) hp[j] = hcar[dir * (B_ * H_) + (mb + j) * H_ + u];
    } else {
        #pragma unroll
        for (int j = 0; j < 4; ++j) hp[j] = 0.f;
    }

    unsigned short xg[3][4];
    auto ldxp = [&](int tl) {
        #pragma unroll
        for (int j = 0; j < 4; ++j) {
            const unsigned short* xb = xp + ((size_t)((mb + j) * TC_ + tl) * G_) + u;
            xg[0][j] = xb[0]; xg[1][j] = xb[H_]; xg[2][j] = xb[2 * H_];
        }
    };
    ldxp(dir ? (TC_ - 1) : 0);

    for (int sl = 0; sl < TC_; ++sl) {
        const int s  = c * TC_ + sl;
        const int gs = layer * T_ + s;
        const int t = dir ? (T_ - 1 - s) : s;
        const int tloc = dir ? (TC_ - 1 - sl) : sl;

        f32x4 z4 = { 0.f, 0.f, 0.f, 0.f };
        f32x4 acc[3];
        acc[0] = z4; acc[1] = z4; acc[2] = z4;

        if (s > 0) {
            const unsigned int rpar = (unsigned int)(((s - 1) & 1) * 16384);
            if (sl > 0) {                  // chunk start: prev launch done via stream order
                int v = gs;
                int tries = 0;
                if (l < 32) v = __hip_atomic_load(pollb + l * 32, __ATOMIC_RELAXED, __HIP_MEMORY_SCOPE_AGENT);
                while (!__all(v >= gs)) {
                    if (++tries > 3) __builtin_amdgcn_s_sleep(1);
                    if (l < 32) v = __hip_atomic_load(pollb + l * 32, __ATOMIC_RELAXED, __HIP_MEMORY_SCOPE_AGENT);
                }
                asm volatile("" ::: "memory");   // no hoist of h loads above poll
            }
            // cooperative stage: h(s-1)[bg*16 .. +15][all 512] -> parity LDS (swizzled)
            {
                const ull* src = (const ull*)(hpub
                    + ((size_t)((((s - 1) & 1) * 2 + dir) * B_ + bg * 16 + srowl)) * 256)
                    + sseg * 8;
                ull qv[8];
                #pragma unroll
                for (int i = 0; i < 8; ++i)
                    qv[i] = __hip_atomic_load(src + i, __ATOMIC_RELAXED, __HIP_MEMORY_SCOPE_AGENT);
                char* dst = smem + rpar + srowl * 1024;
                #pragma unroll
                for (int i = 0; i < 4; ++i) {
                    unsigned int byt = (unsigned int)(sseg * 64 + i * 16);
                    byt ^= ((unsigned int)(srowl & 7)) << 4;
                    union { ull qq[2]; u32x4 v4; } pk;
                    pk.qq[0] = qv[2 * i]; pk.qq[1] = qv[2 * i + 1];
                    *(u32x4*)(dst + byt) = pk.v4;
                }
            }
            __syncthreads();               // the single per-step barrier (stage -> read)
            #pragma unroll
            for (int ks = 0; ks < 16; ++ks) {
                unsigned int byt = (unsigned int)(ks * 64 + q * 16);
                byt ^= ((unsigned int)(fl & 7)) << 4;
                bf16x8 afr = *(const bf16x8*)(smem + rpar + fl * 1024 + byt);
                acc[0] = MFMA16(afr, wv[0][ks], acc[0]);
                acc[1] = MFMA16(afr, wv[1][ks], acc[1]);
                acc[2] = MFMA16(afr, wv[2][ks], acc[2]);
            }
        }

        unsigned short hb16s[4];
        #pragma unroll
        for (int j = 0; j < 4; ++j) {
            float xr = bf2f(xg[0][j]);
            float xz = bf2f(xg[1][j]);
            float xn = bf2f(xg[2][j]);
            float r = sigm(xr + acc[0][j] + br_);
            float z = sigm(xz + acc[1][j] + bz_);
            float nn = tanh_(xn + r * (acc[2][j] + bn_));
            float hv = (1.f - z) * nn + z * hp[j];
            hp[j] = hv;
            hb16s[j] = f2bf(hv);
        }

        // packed h stores (even-fl lanes) FIRST ...
        unsigned int* hw = hpub + (size_t)((s & 1) * 2 + dir) * (B_ * 256);
        #pragma unroll
        for (int j = 0; j < 4; ++j) {
            unsigned int pv = (unsigned int)(unsigned short)__shfl_xor((int)hb16s[j], 1);
            if ((fl & 1) == 0) {
                unsigned int pk32 = (unsigned int)hb16s[j] | (pv << 16);
                __hip_atomic_store(hw + (size_t)(mb + j) * 256 + (u >> 1), pk32,
                                   __ATOMIC_RELAXED, __HIP_MEMORY_SCOPE_AGENT);
            }
        }
        asm volatile("" ::: "memory");     // pin issue order: h stores before the below
        // ... then outp stores + next-xp prefetch issue UNDER the h-store ack RT
        #pragma unroll
        for (int j = 0; j < 4; ++j) {
            size_t row = mode ? (size_t)((mb + j) * TC_ + tloc) : ((size_t)(mb + j) * T_ + t);
            outp[row * ldo + u] = hb16s[j];
        }
        if (sl < TC_ - 1) ldxp(dir ? (TC_ - 2 - sl) : (sl + 1));
        // counted wait: <=16 outstanding => the 4 older h stores are acked
        asm volatile("s_waitcnt vmcnt(16)" ::: "memory");
        if (l == 0)                        // per-WAVE flag: own 16-unit slice done
            __hip_atomic_store(myflag, gs + 1, __ATOMIC_RELAXED, __HIP_MEMORY_SCOPE_AGENT);
    }

    #pragma unroll
    for (int j = 0; j < 4; ++j) hcar[dir * (B_ * H_) + (mb + j) * H_ + u] = hp[j];
}

// ---------------- CRF: one block (one wave) per batch element ----------------
__global__ __launch_bounds__(64) void crf_kernel(const float* __restrict__ em,     // [BT][K]
                                                 const int* __restrict__ labels,
                                                 const float* __restrict__ start,
                                                 const float* __restrict__ endv,
                                                 const float* __restrict__ trans,
                                                 float* __restrict__ partials) {
    __shared__ float tr[32 * 32];
    const int b = blockIdx.x, l = threadIdx.x;
    for (int e2 = l; e2 < 961; e2 += 64) {
        int r = e2 / 31, cc = e2 - r * 31;
        tr[r * 32 + cc] = trans[e2];
    }
    if (l < 32) tr[31 * 32 + l] = 0.f;
    __syncthreads();
    const int* lab = labels + b * T_;
    const float* eb = em + (size_t)b * T_ * K_;

    float part = 0.f, cnt = 0.f;
    for (int t = l; t < T_; t += 64) {
        int lt = lab[t];
        if (lt > -1) {
            cnt += 1.f;
            if (t > 0) part += tr[lab[t - 1] * 32 + lt] + eb[t * K_ + lt];
        }
    }
    #pragma unroll
    for (int o = 32; o; o >>= 1) { part += __shfl_xor(part, o); cnt += __shfl_xor(cnt, o); }
    int lastidx = (int)cnt - 1;
    float num = part + start[lab[0]] + eb[lab[0]] + endv[lab[lastidx]];

    const int jj = l & 31, half = l >> 5;
    const int i0 = half * 16;
    const int ecol = (jj < K_) ? jj : (K_ - 1);
    float a = (jj < K_) ? (start[jj] + eb[jj]) : -3.0e38f;
    for (int t = 1; t < T_; ++t) {
        float tv[16];
        float m = -3.0e38f;
        #pragma unroll
        for (int k = 0; k < 16; ++k) {
            float av = __shfl(a, i0 + k);
            float x = av + tr[(i0 + k) * 32 + jj];
            tv[k] = x;
            m = fmaxf(m, x);
        }
        float ss = 0.f;
        #pragma unroll
        for (int k = 0; k < 16; ++k) ss += __expf(tv[k] - m);
        float m2 = __shfl_xor(m, 32), s2 = __shfl_xor(ss, 32);
        float M = fmaxf(m, m2);
        float S = ss * __expf(m - M) + s2 * __expf(m2 - M);
        float anew = eb[t * K_ + ecol] + M + __logf(S);
        a = ((lab[t] > -1) && (jj < K_)) ? anew : a;
    }
    float v = (jj < K_) ? (a + endv[jj]) : -3.0e38f;
    float m = v;
    #pragma unroll
    for (int o = 32; o; o >>= 1) m = fmaxf(m, __shfl_xor(m, o));
    float ss = (half == 0 && jj < K_) ? __expf(v - m) : 0.f;
    #pragma unroll
    for (int o = 32; o; o >>= 1) ss += __shfl_xor(ss, o);
    if (l == 0) partials[b] = num - (m + __logf(ss));
}

__global__ __launch_bounds__(64) void loss_reduce(const float* __restrict__ partials,
                                                  float* __restrict__ out) {
    float v = partials[threadIdx.x];
    #pragma unroll
    for (int o = 32; o; o >>= 1) v += __shfl_xor(v, o);
    if (threadIdx.x == 0) out[0] = -v;
}

__global__ void sentinel(float* __restrict__ out, float v) { out[0] = -v; }

// ---------------- host ----------------
extern "C" void kernel_launch(void* const* d_in, const int* in_sizes, int n_in,
                              void* d_out, int out_size, void* d_ws, size_t ws_size,
                              hipStream_t stream) {
    const int*   ids      = (const int*)d_in[0];
    const int*   labels   = (const int*)d_in[1];
    const float* emb      = (const float*)d_in[2];
    const float* wih[4]   = { (const float*)d_in[3], (const float*)d_in[7], (const float*)d_in[11], (const float*)d_in[15] };
    const float* whh[4]   = { (const float*)d_in[4], (const float*)d_in[8], (const float*)d_in[12], (const float*)d_in[16] };
    const float* bih[4]   = { (const float*)d_in[5], (const float*)d_in[9], (const float*)d_in[13], (const float*)d_in[17] };
    const float* bhh[4]   = { (const float*)d_in[6], (const float*)d_in[10], (const float*)d_in[14], (const float*)d_in[18] };
    const float* cls_w    = (const float*)d_in[19];
    const float* cls_b    = (const float*)d_in[20];
    const float* c_start  = (const float*)d_in[21];
    const float* c_end    = (const float*)d_in[22];
    const float* c_trans  = (const float*)d_in[23];
    float* out = (float*)d_out;
    float* out1 = out + 1;

    char* p = (char*)d_ws;
    size_t used = 0;
    auto alloc = [&](size_t bytes) -> char* {
        char* r = p;
        size_t a = (bytes + 255) & ~(size_t)255;
        p += a; used += a;
        return r;
    };
    unsigned short* xpF[2]; unsigned short* xpB[2];
    for (int i = 0; i < 2; ++i) {
        xpF[i] = (unsigned short*)alloc((size_t)B_ * TC_ * G_ * 2);   // 12.6MB each
        xpB[i] = (unsigned short*)alloc((size_t)B_ * TC_ * G_ * 2);
    }
    unsigned short* h1   = (unsigned short*)alloc((size_t)BT_ * H2_ * 2);       // 67MB
    unsigned short* goF[2]; unsigned short* goB[2];
    for (int i = 0; i < 2; ++i) {
        goF[i] = (unsigned short*)alloc((size_t)B_ * TC_ * H_ * 2);             // 4.2MB each
        goB[i] = (unsigned short*)alloc((size_t)B_ * TC_ * H_ * 2);
    }
    unsigned short* clsf  = (unsigned short*)alloc((size_t)32 * H_ * 2);
    unsigned short* clshb = (unsigned short*)alloc((size_t)32 * H_ * 2);
    unsigned short* whhbf = (unsigned short*)alloc((size_t)G_ * H_ * 2);        // per-layer, re-cvt
    unsigned short* whhbb = (unsigned short*)alloc((size_t)G_ * H_ * 2);
    unsigned short* wihbf = (unsigned short*)alloc((size_t)G_ * H2_ * 2);       // 3.1MB, per-layer
    unsigned short* wihbb = (unsigned short*)alloc((size_t)G_ * H2_ * 2);
    unsigned int*   hpub  = (unsigned int*)alloc((size_t)2 * 2 * B_ * 256 * 4); // 512KB
    float*          hcar  = (float*)alloc((size_t)2 * B_ * H_ * 4);             // 256KB
    float*          partials = (float*)alloc((size_t)B_ * 4);
    int*            flags = (int*)alloc((size_t)2 * 4 * 32 * 32 * 4);           // 32KB

    if (used > ws_size) {
        sentinel<<<dim3(1), dim3(1), 0, stream>>>(out, (float)(ws_size >> 20));
        return;
    }

    hipMemsetAsync(flags, 0, (size_t)2 * 4 * 32 * 32 * 4, stream);
    cvt_cls<<<dim3((32 * H_ + 255) / 256), dim3(256), 0, stream>>>(cls_w, clsf, clshb);
    emis_bias_init<<<dim3(1024), dim3(256), 0, stream>>>(cls_b, out1);

    for (int layer = 0; layer < 2; ++layer) {
        const float* bf_ = bih[layer * 2 + 0];
        const float* bb_ = bih[layer * 2 + 1];
        const float* bhf = bhh[layer * 2 + 0];
        const float* bhb = bhh[layer * 2 + 1];
        const int lda = layer ? H2_ : E_;

        // convert this layer's weights -> bf16 (stream-ordered, deterministic)
        cvt_f32_bf16<<<dim3(2048), dim3(256), 0, stream>>>(whh[layer * 2 + 0], whhbf, G_ * H_);
        cvt_f32_bf16<<<dim3(2048), dim3(256), 0, stream>>>(whh[layer * 2 + 1], whhbb, G_ * H_);
        cvt_f32_bf16<<<dim3(2048), dim3(256), 0, stream>>>(wih[layer * 2 + 0], wihbf, G_ * lda);
        cvt_f32_bf16<<<dim3(2048), dim3(256), 0, stream>>>(wih[layer * 2 + 1], wihbb, G_ * lda);

        // chunk-0 xp GEMMs (standalone, full grid, bf16 W)
        if (layer == 0) {
            gemm_k<false, false, true><<<dim3(64, 24), dim3(256), 0, stream>>>(
                nullptr, emb, ids, E_, 0, T_, wihbf, E_, G_, bf_, (void*)xpF[0], G_, 0, TC_, G_, E_);
            gemm_k<false, false, true><<<dim3(64, 24), dim3(256), 0, stream>>>(
                nullptr, emb, ids, E_, T_ - TC_, T_, wihbb, E_, G_, bb_, (void*)xpB[0], G_, 0, TC_, G_, E_);
        } else {
            gemm_k<false, false, false><<<dim3(64, 24), dim3(256), 0, stream>>>(
                h1, nullptr, nullptr, H2_, 0, T_, wihbf, H2_, G_, bf_, (void*)xpF[0], G_, 0, TC_, G_, H2_);
            gemm_k<false, false, false><<<dim3(64, 24), dim3(256), 0, stream>>>(
                h1, nullptr, nullptr, H2_, T_ - TC_, T_, wihbb, H2_, G_, bb_, (void*)xpB[0], G_, 0, TC_, G_, H2_);
        }

        for (int c = 0; c < NC_; ++c) {
            int dg = (c + 1 < NC_) ? 1 : 0;
            int t0f_n = (c + 1) * TC_;
            int t0b_n = T_ - (c + 2) * TC_;
            if (layer == 0) {
                fused_scan_gemm<true><<<dim3(256), dim3(256), 0, stream>>>(
                    c, 0, xpF[c & 1], xpB[c & 1], whhbf, whhbb, bhf, bhb, hpub, hcar,
                    h1, h1 + H_, H2_, 0, flags,
                    nullptr, emb, ids, E_, wihbf, wihbb, bf_, bb_,
                    xpF[(c + 1) & 1], xpB[(c + 1) & 1], t0f_n, t0b_n, dg,
                    nullptr, nullptr, nullptr, nullptr, nullptr, 0, 0, 0);
            } else {
                int de = (c > 0) ? 1 : 0;
                int t0f_e = (c - 1) * TC_;
                int t0b_e = T_ - c * TC_;
                fused_scan_gemm<false><<<dim3(256), dim3(256), 0, stream>>>(
                    c, 1, xpF[c & 1], xpB[c & 1], whhbf, whhbb, bhf, bhb, hpub, hcar,
                    goF[c & 1], goB[c & 1], H_, 1, flags,
                    h1, nullptr, nullptr, H2_, wihbf, wihbb, bf_, bb_,
                    xpF[(c + 1) & 1], xpB[(c + 1) & 1], t0f_n, t0b_n, dg,
                    goF[(c + 1) & 1], goB[(c + 1) & 1], clsf, clshb, out1, t0f_e, t0b_e, de);
            }
        }
    }

    // final chunk's emissions (NC_-1)
    emis_k<<<dim3(64, 2), dim3(256), 0, stream>>>(goF[(NC_ - 1) & 1], goB[(NC_ - 1) & 1],
        clsf, clshb, out1, (NC_ - 1) * TC_, 0);

    crf_kernel<<<dim3(B_), dim3(64), 0, stream>>>(out1, labels, c_start, c_end, c_trans, partials);
    loss_reduce<<<dim3(1), dim3(64), 0, stream>>>(partials, out);
}